// Round 9
// baseline (1974.276 us; speedup 1.0000x reference)
//
#include <hip/hip_runtime.h>
#include <math.h>

#define N_NODES 50000
#define N_EDGES 1600000
#define NBATCH  64
#define INCH    128
#define HEADS   8
#define HD      8
#define GH      64
#define HIDDEN  64
#define NC      10
#define NEG_SLOPE 0.2f
#define BN_EPS  1e-5f

#define SCAN_TPB 1024
#define NTILES   ((N_NODES + SCAN_TPB - 1) / SCAN_TPB)   // 49

typedef unsigned short ushort_t;
typedef unsigned int uint_t;

__device__ __forceinline__ ushort_t f2bf(float f) {
  uint_t u = __float_as_uint(f);
  uint_t r = (u + 0x7fffu + ((u >> 16) & 1u)) >> 16;   // RNE
  return (ushort_t)r;
}
// unpack 2 bf16 from one uint: low half -> .x, high half -> .y
__device__ __forceinline__ float2 upk(uint_t u) {
  return make_float2(__uint_as_float(u << 16), __uint_as_float(u & 0xffff0000u));
}
// unpack uint4 (8 bf16) -> 8 floats
__device__ __forceinline__ void upk8(uint4 u, float* v) {
  float2 t;
  t = upk(u.x); v[0] = t.x; v[1] = t.y;
  t = upk(u.y); v[2] = t.x; v[3] = t.y;
  t = upk(u.z); v[4] = t.x; v[5] = t.y;
  t = upk(u.w); v[6] = t.x; v[7] = t.y;
}

// ---------------- edge pass: gaussian weights + per-dst count/sum ----------------
__global__ __launch_bounds__(256) void edge_kernel(
    const int* __restrict__ ei, const float* __restrict__ raw,
    float* __restrict__ ea, float* __restrict__ easum, int* __restrict__ cnt) {
  int e = blockIdx.x * blockDim.x + threadIdx.x;
  if (e >= N_EDGES) return;
  int s = ei[e], d = ei[N_EDGES + e];
  float dx = raw[s*3+0] - raw[d*3+0];
  float dy = raw[s*3+1] - raw[d*3+1];
  float dz = raw[s*3+2] - raw[d*3+2];
  float w = __expf(-2.0f * (dx*dx + dy*dy + dz*dz));   // sigma=0.5 -> /(2*0.25)
  ea[e] = w;
  atomicAdd(&easum[d], w);
  atomicAdd(&cnt[d], 1);
}

// ---------------- CSR build: 3-phase scan + scatter ----------------
__global__ __launch_bounds__(SCAN_TPB) void scan_part(
    const int* __restrict__ cnt, const float* __restrict__ easum,
    int* __restrict__ rowptr, float* __restrict__ loopat, int* __restrict__ bsum) {
  __shared__ int s[SCAN_TPB];
  int t = threadIdx.x;
  int i = blockIdx.x * SCAN_TPB + t;
  int v = (i < N_NODES) ? cnt[i] : 0;
  s[t] = v; __syncthreads();
  for (int off = 1; off < SCAN_TPB; off <<= 1) {
    int u = (t >= off) ? s[t - off] : 0;
    __syncthreads();
    s[t] += u;
    __syncthreads();
  }
  if (i < N_NODES) {
    rowptr[i] = s[t] - v;                          // block-local exclusive
    loopat[i] = easum[i] / fmaxf((float)v, 1.0f);  // self-loop attr (mean)
  }
  if (t == SCAN_TPB - 1) bsum[blockIdx.x] = s[t];
}

__global__ __launch_bounds__(64) void scan_top(int* __restrict__ bsum, int* __restrict__ rowptr) {
  int t = threadIdx.x;
  int v = (t < NTILES) ? bsum[t] : 0;
  int orig = v;
  for (int off = 1; off < 64; off <<= 1) {
    int u = __shfl_up(v, off);
    if (t >= off) v += u;
  }
  if (t < NTILES) bsum[t] = v - orig;   // exclusive block offsets
  if (t == 0) rowptr[N_NODES] = N_EDGES;
}

__global__ __launch_bounds__(SCAN_TPB) void scan_add(int* __restrict__ rowptr, const int* __restrict__ bsum) {
  int i = blockIdx.x * SCAN_TPB + threadIdx.x;
  if (i < N_NODES) rowptr[i] += bsum[blockIdx.x];
}

__global__ __launch_bounds__(256) void scatter_kernel(
    const int* __restrict__ ei, const float* __restrict__ ea,
    const int* __restrict__ rowptr, int* __restrict__ cnt2,
    int* __restrict__ csr_src, float* __restrict__ csr_ea) {
  int e = blockIdx.x * blockDim.x + threadIdx.x;
  if (e >= N_EDGES) return;
  int s = ei[e], d = ei[N_EDGES + e];
  int pos = rowptr[d] + atomicAdd(&cnt2[d], 1);
  csr_src[pos] = s;
  csr_ea[pos] = ea[e];
}

// ---------------- GEMM1: h1 = x @ W1 (bf16 rows) ----------------
__global__ __launch_bounds__(256) void gemm1_kernel(
    const float* __restrict__ x, const float* __restrict__ W1,
    ushort_t* __restrict__ h1b) {
  __shared__ float w[INCH * GH];   // 32 KB
  for (int i = threadIdx.x; i < INCH * GH / 4; i += blockDim.x)
    ((float4*)w)[i] = ((const float4*)W1)[i];
  __syncthreads();
  int lane = threadIdx.x & 63;
  int waveG = __builtin_amdgcn_readfirstlane((blockIdx.x * blockDim.x + threadIdx.x) >> 6);
  int nWaves = (gridDim.x * blockDim.x) >> 6;
  for (int base = waveG * 4; base < N_NODES; base += nWaves * 4) {   // N % 4 == 0
    float acc[4] = {0.f, 0.f, 0.f, 0.f};
    #pragma unroll 8
    for (int k = 0; k < INCH; ++k) {
      float wv = w[k * GH + lane];
      #pragma unroll
      for (int j = 0; j < 4; ++j)
        acc[j] = fmaf(x[(size_t)(base + j) * INCH + k], wv, acc[j]);
    }
    #pragma unroll
    for (int j = 0; j < 4; ++j)
      h1b[(size_t)(base + j) * GH + lane] = f2bf(acc[j]);
  }
}

// ---------------- conv1: 16-edge-flight, zero-shfl inner loop, per-head softmax ----------
// lane = 4*g + c; group g (0..15) owns edge (batch*16+g); chunk c covers dims 16c..16c+15
// = heads 2c (first uint4) and 2c+1 (second uint4). No cross-lane ops inside the loop.
// Self-loop is added AFTER the cross-group fold (adding it before would count it 16x).
__global__ __launch_bounds__(256) void conv1_kernel(
    const ushort_t* __restrict__ h1b,
    const float* __restrict__ asrc, const float* __restrict__ adst,
    const float* __restrict__ We, const float* __restrict__ ae,
    const int* __restrict__ rowptr,
    const int* __restrict__ csr_src, const float* __restrict__ csr_ea,
    const float* __restrict__ loopat, const float* __restrict__ bias,
    const float* __restrict__ gamma, const float* __restrict__ beta,
    const float* __restrict__ rm, const float* __restrict__ rv,
    float* __restrict__ h2) {
  __shared__ int   src_lds[4][64];
  __shared__ float ea_lds[4][64];
  int l = threadIdx.x & 63;
  int w = threadIdx.x >> 6;
  int n = blockIdx.x * 4 + w;
  if (n >= N_NODES) return;
  int g = l >> 2;
  int c = l & 3;
  // per-lane attention slices (dims 16c .. 16c+15)
  float as[16];
  float ce0 = 0.f, ce1 = 0.f;
  float ad[16];
  #pragma unroll
  for (int k = 0; k < 4; ++k) {
    float4 t = ((const float4*)asrc)[c*4 + k];
    as[4*k+0] = t.x; as[4*k+1] = t.y; as[4*k+2] = t.z; as[4*k+3] = t.w;
    float4 d = ((const float4*)adst)[c*4 + k];
    ad[4*k+0] = d.x; ad[4*k+1] = d.y; ad[4*k+2] = d.z; ad[4*k+3] = d.w;
    float4 wv = ((const float4*)We)[c*4 + k];
    float4 av = ((const float4*)ae)[c*4 + k];
    float s = wv.x*av.x + wv.y*av.y + wv.z*av.z + wv.w*av.w;
    if (k < 2) ce0 += s; else ce1 += s;
  }
  const uint4* tab4 = (const uint4*)h1b;          // row = 8 x uint4 (128 B)
  // own row
  uint4 sr0 = tab4[(size_t)n*8 + c*2];
  uint4 sr1 = tab4[(size_t)n*8 + c*2 + 1];
  float sv0[8], sv1[8];
  upk8(sr0, sv0); upk8(sr1, sv1);
  float als0 = 0.f, als1 = 0.f, ald0 = 0.f, ald1 = 0.f;
  #pragma unroll
  for (int j = 0; j < 8; ++j) {
    als0 = fmaf(sv0[j], as[j], als0);
    ald0 = fmaf(sv0[j], ad[j], ald0);
    als1 = fmaf(sv1[j], as[8+j], als1);
    ald1 = fmaf(sv1[j], ad[8+j], ald1);
  }
  int jb = rowptr[n], je = rowptr[n + 1];
  float ssum0 = 0.f, ssum1 = 0.f;
  float a[16];
  #pragma unroll
  for (int k = 0; k < 16; ++k) a[k] = 0.f;
  for (int cb = jb; cb < je; cb += 64) {
    int cnt = je - cb; if (cnt > 64) cnt = 64;
    int idx = cb + l;
    bool vld = l < cnt;
    src_lds[w][l] = vld ? csr_src[idx] : 0;
    ea_lds[w][l]  = vld ? csr_ea[idx] : 0.f;
    int nb = (cnt + 15) >> 4;
    int j0 = g;
    int s0 = (j0 < cnt) ? src_lds[w][j0] : 0;
    uint4 r0 = tab4[(size_t)s0*8 + c*2];
    uint4 r1 = tab4[(size_t)s0*8 + c*2 + 1];
    for (int b = 0; b < nb; ++b) {
      uint4 n0 = r0, n1 = r1;
      if (b + 1 < nb) {
        int jn = ((b + 1) << 4) + g;
        int sn = (jn < cnt) ? src_lds[w][jn] : 0;
        n0 = tab4[(size_t)sn*8 + c*2];
        n1 = tab4[(size_t)sn*8 + c*2 + 1];
      }
      int j = (b << 4) + g;
      bool val = j < cnt;
      float eav = val ? ea_lds[w][j] : 0.f;
      float v0[8], v1[8];
      upk8(r0, v0); upk8(r1, v1);
      float dp0 = 0.f, dp1 = 0.f;
      #pragma unroll
      for (int k = 0; k < 8; ++k) {
        dp0 = fmaf(v0[k], as[k], dp0);
        dp1 = fmaf(v1[k], as[8+k], dp1);
      }
      float lg0 = dp0 + ald0 + eav * ce0;
      float lg1 = dp1 + ald1 + eav * ce1;
      lg0 = (lg0 >= 0.f) ? lg0 : NEG_SLOPE * lg0;
      lg1 = (lg1 >= 0.f) ? lg1 : NEG_SLOPE * lg1;
      lg0 = val ? lg0 : -1e30f;
      lg1 = val ? lg1 : -1e30f;
      float p0 = __expf(fminf(lg0, 60.f));
      float p1 = __expf(fminf(lg1, 60.f));
      ssum0 += p0; ssum1 += p1;
      #pragma unroll
      for (int k = 0; k < 8; ++k) {
        a[k]   = fmaf(p0, v0[k], a[k]);
        a[8+k] = fmaf(p1, v1[k], a[8+k]);
      }
      r0 = n0; r1 = n1;
    }
  }
  // fold across the 16 groups (once per node)
  ssum0 += __shfl_xor(ssum0, 4); ssum0 += __shfl_xor(ssum0, 8);
  ssum0 += __shfl_xor(ssum0, 16); ssum0 += __shfl_xor(ssum0, 32);
  ssum1 += __shfl_xor(ssum1, 4); ssum1 += __shfl_xor(ssum1, 8);
  ssum1 += __shfl_xor(ssum1, 16); ssum1 += __shfl_xor(ssum1, 32);
  #pragma unroll
  for (int k = 0; k < 16; ++k) {
    a[k] += __shfl_xor(a[k], 4);  a[k] += __shfl_xor(a[k], 8);
    a[k] += __shfl_xor(a[k], 16); a[k] += __shfl_xor(a[k], 32);
  }
  // self loop — AFTER fold; every lane holds full sums, add identically once
  {
    float la = loopat[n];
    float lg0 = als0 + ald0 + la * ce0;
    float lg1 = als1 + ald1 + la * ce1;
    lg0 = (lg0 >= 0.f) ? lg0 : NEG_SLOPE * lg0;
    lg1 = (lg1 >= 0.f) ? lg1 : NEG_SLOPE * lg1;
    float p0 = __expf(fminf(lg0, 60.f));
    float p1 = __expf(fminf(lg1, 60.f));
    ssum0 += p0; ssum1 += p1;
    #pragma unroll
    for (int k = 0; k < 8; ++k) {
      a[k]   = fmaf(p0, sv0[k], a[k]);
      a[8+k] = fmaf(p1, sv1[k], a[8+k]);
    }
  }
  if (g == 0) {
    float inv0 = 1.0f / ssum0, inv1 = 1.0f / ssum1;
    float o[16];
    #pragma unroll
    for (int k = 0; k < 16; ++k) {
      int d = c*16 + k;
      float ov = a[k] * ((k < 8) ? inv0 : inv1) + bias[d];
      ov = (ov - rm[d]) * (gamma[d] * rsqrtf(rv[d] + BN_EPS)) + beta[d];
      o[k] = (ov > 0.f) ? ov : expm1f(ov);
    }
    float4* dst = (float4*)(h2 + (size_t)n * GH);
    #pragma unroll
    for (int k = 0; k < 4; ++k)
      dst[c*4 + k] = make_float4(o[4*k], o[4*k+1], o[4*k+2], o[4*k+3]);
  }
}

// ---------------- GEMM2: h2m = h2 @ W2 (bf16 rows) ----------------
__global__ __launch_bounds__(256) void gemm2_kernel(
    const float* __restrict__ x, const float* __restrict__ W2,
    ushort_t* __restrict__ h2mb) {
  __shared__ float w[HIDDEN * HIDDEN];   // 16 KB
  for (int i = threadIdx.x; i < HIDDEN * HIDDEN / 4; i += blockDim.x)
    ((float4*)w)[i] = ((const float4*)W2)[i];
  __syncthreads();
  int lane = threadIdx.x & 63;
  int waveG = __builtin_amdgcn_readfirstlane((blockIdx.x * blockDim.x + threadIdx.x) >> 6);
  int nWaves = (gridDim.x * blockDim.x) >> 6;
  for (int base = waveG * 4; base < N_NODES; base += nWaves * 4) {
    float acc[4] = {0.f, 0.f, 0.f, 0.f};
    #pragma unroll 8
    for (int k = 0; k < HIDDEN; ++k) {
      float wv = w[k * HIDDEN + lane];
      #pragma unroll
      for (int j = 0; j < 4; ++j)
        acc[j] = fmaf(x[(size_t)(base + j) * HIDDEN + k], wv, acc[j]);
    }
    #pragma unroll
    for (int j = 0; j < 4; ++j)
      h2mb[(size_t)(base + j) * HIDDEN + lane] = f2bf(acc[j]);
  }
}

// ---------------- conv2 (heads=1): 16-edge-flight, 2-shfl inner loop ----------------
// Self-loop added AFTER the cross-group fold (same fix as conv1).
__global__ __launch_bounds__(256) void conv2_kernel(
    const ushort_t* __restrict__ h2mb,
    const float* __restrict__ asrc, const float* __restrict__ adst,
    const float* __restrict__ We, const float* __restrict__ ae,
    const int* __restrict__ rowptr,
    const int* __restrict__ csr_src, const float* __restrict__ csr_ea,
    const float* __restrict__ loopat, const float* __restrict__ bias,
    const float* __restrict__ gamma, const float* __restrict__ beta,
    const float* __restrict__ rm, const float* __restrict__ rv,
    const int* __restrict__ batch,
    float* __restrict__ pool, int* __restrict__ cntg) {
  __shared__ int   src_lds[4][64];
  __shared__ float ea_lds[4][64];
  int l = threadIdx.x & 63;
  int w = threadIdx.x >> 6;
  int n = blockIdx.x * 4 + w;
  if (n >= N_NODES) return;
  int g = l >> 2;
  int c = l & 3;
  float as[16];
  float cep = 0.f;
  float ad[16];
  #pragma unroll
  for (int k = 0; k < 4; ++k) {
    float4 t = ((const float4*)asrc)[c*4 + k];
    as[4*k+0] = t.x; as[4*k+1] = t.y; as[4*k+2] = t.z; as[4*k+3] = t.w;
    float4 d = ((const float4*)adst)[c*4 + k];
    ad[4*k+0] = d.x; ad[4*k+1] = d.y; ad[4*k+2] = d.z; ad[4*k+3] = d.w;
    float4 wv = ((const float4*)We)[c*4 + k];
    float4 av = ((const float4*)ae)[c*4 + k];
    cep += wv.x*av.x + wv.y*av.y + wv.z*av.z + wv.w*av.w;
  }
  float ce = cep;
  ce += __shfl_xor(ce, 1); ce += __shfl_xor(ce, 2);   // sum over 4 chunks = 64 dims
  const uint4* tab4 = (const uint4*)h2mb;
  uint4 sr0 = tab4[(size_t)n*8 + c*2];
  uint4 sr1 = tab4[(size_t)n*8 + c*2 + 1];
  float sv0[8], sv1[8];
  upk8(sr0, sv0); upk8(sr1, sv1);
  float alsp = 0.f, aldp = 0.f;
  #pragma unroll
  for (int j = 0; j < 8; ++j) {
    alsp = fmaf(sv0[j], as[j], alsp);
    alsp = fmaf(sv1[j], as[8+j], alsp);
    aldp = fmaf(sv0[j], ad[j], aldp);
    aldp = fmaf(sv1[j], ad[8+j], aldp);
  }
  float als_s = alsp; als_s += __shfl_xor(als_s, 1); als_s += __shfl_xor(als_s, 2);
  float aldn  = aldp; aldn  += __shfl_xor(aldn, 1);  aldn  += __shfl_xor(aldn, 2);
  int jb = rowptr[n], je = rowptr[n + 1];
  float ssum = 0.f;
  float a[16];
  #pragma unroll
  for (int k = 0; k < 16; ++k) a[k] = 0.f;
  for (int cb = jb; cb < je; cb += 64) {
    int cnt = je - cb; if (cnt > 64) cnt = 64;
    int idx = cb + l;
    bool vld = l < cnt;
    src_lds[w][l] = vld ? csr_src[idx] : 0;
    ea_lds[w][l]  = vld ? csr_ea[idx] : 0.f;
    int nb = (cnt + 15) >> 4;
    int j0 = g;
    int s0 = (j0 < cnt) ? src_lds[w][j0] : 0;
    uint4 r0 = tab4[(size_t)s0*8 + c*2];
    uint4 r1 = tab4[(size_t)s0*8 + c*2 + 1];
    for (int b = 0; b < nb; ++b) {
      uint4 n0 = r0, n1 = r1;
      if (b + 1 < nb) {
        int jn = ((b + 1) << 4) + g;
        int sn = (jn < cnt) ? src_lds[w][jn] : 0;
        n0 = tab4[(size_t)sn*8 + c*2];
        n1 = tab4[(size_t)sn*8 + c*2 + 1];
      }
      int j = (b << 4) + g;
      bool val = j < cnt;
      float eav = val ? ea_lds[w][j] : 0.f;
      float v0[8], v1[8];
      upk8(r0, v0); upk8(r1, v1);
      float dp = 0.f;
      #pragma unroll
      for (int k = 0; k < 8; ++k) {
        dp = fmaf(v0[k], as[k], dp);
        dp = fmaf(v1[k], as[8+k], dp);
      }
      dp += __shfl_xor(dp, 1); dp += __shfl_xor(dp, 2);   // full 64-dim dot
      float lg = dp + aldn + eav * ce;
      lg = (lg >= 0.f) ? lg : NEG_SLOPE * lg;
      lg = val ? lg : -1e30f;
      float p = __expf(fminf(lg, 60.f));
      ssum += p;
      #pragma unroll
      for (int k = 0; k < 8; ++k) {
        a[k]   = fmaf(p, v0[k], a[k]);
        a[8+k] = fmaf(p, v1[k], a[8+k]);
      }
      r0 = n0; r1 = n1;
    }
  }
  // fold across groups (ssum identical within a group; fold only across g)
  ssum += __shfl_xor(ssum, 4); ssum += __shfl_xor(ssum, 8);
  ssum += __shfl_xor(ssum, 16); ssum += __shfl_xor(ssum, 32);
  #pragma unroll
  for (int k = 0; k < 16; ++k) {
    a[k] += __shfl_xor(a[k], 4);  a[k] += __shfl_xor(a[k], 8);
    a[k] += __shfl_xor(a[k], 16); a[k] += __shfl_xor(a[k], 32);
  }
  // self loop — AFTER fold
  {
    float lg = als_s + aldn + loopat[n] * ce;
    lg = (lg >= 0.f) ? lg : NEG_SLOPE * lg;
    float p = __expf(fminf(lg, 60.f));
    ssum += p;
    #pragma unroll
    for (int k = 0; k < 8; ++k) {
      a[k]   = fmaf(p, sv0[k], a[k]);
      a[8+k] = fmaf(p, sv1[k], a[8+k]);
    }
  }
  if (g == 0) {
    float inv = 1.0f / ssum;
    int b = batch[n];
    float* pp = pool + (size_t)b * HIDDEN + 16 * c;
    #pragma unroll
    for (int k = 0; k < 16; ++k) {
      int d = c*16 + k;
      float ov = a[k] * inv + bias[d];
      ov = (ov - rm[d]) * (gamma[d] * rsqrtf(rv[d] + BN_EPS)) + beta[d];
      ov = (ov > 0.f) ? ov : expm1f(ov);
      atomicAdd(pp + k, ov);
    }
    if (l == 0) atomicAdd(&cntg[b], 1);
  }
}

// ---------------- classifier ----------------
__global__ __launch_bounds__(640) void final_kernel(
    const float* __restrict__ pool, const int* __restrict__ cntg,
    const float* __restrict__ Wc, const float* __restrict__ bc,
    float* __restrict__ out) {
  int t = threadIdx.x;
  if (t >= NBATCH * NC) return;
  int b = t / NC, c = t - b * NC;
  float inv = 1.0f / fmaxf((float)cntg[b], 1.0f);
  float s = bc[c];
  #pragma unroll
  for (int d = 0; d < HIDDEN; ++d)
    s = fmaf(pool[b * HIDDEN + d] * inv, Wc[d * NC + c], s);
  out[t] = s;
}

extern "C" void kernel_launch(void* const* d_in, const int* in_sizes, int n_in,
                              void* d_out, int out_size, void* d_ws, size_t ws_size,
                              hipStream_t stream) {
  const float* x     = (const float*)d_in[0];
  const float* raw   = (const float*)d_in[1];
  const int*   ei    = (const int*)  d_in[2];
  const int*   batch = (const int*)  d_in[3];
  const float* W1    = (const float*)d_in[4];
  const float* asrc1 = (const float*)d_in[5];
  const float* adst1 = (const float*)d_in[6];
  const float* We1   = (const float*)d_in[7];
  const float* ae1   = (const float*)d_in[8];
  const float* b1    = (const float*)d_in[9];
  const float* g1    = (const float*)d_in[10];
  const float* be1   = (const float*)d_in[11];
  const float* rm1   = (const float*)d_in[12];
  const float* rv1   = (const float*)d_in[13];
  const float* W2    = (const float*)d_in[14];
  const float* asrc2 = (const float*)d_in[15];
  const float* adst2 = (const float*)d_in[16];
  const float* We2   = (const float*)d_in[17];
  const float* ae2   = (const float*)d_in[18];
  const float* b2    = (const float*)d_in[19];
  const float* g2    = (const float*)d_in[20];
  const float* be2   = (const float*)d_in[21];
  const float* rm2   = (const float*)d_in[22];
  const float* rv2   = (const float*)d_in[23];
  const float* Wc    = (const float*)d_in[24];
  const float* bc    = (const float*)d_in[25];
  float* out = (float*)d_out;

  char* ws = (char*)d_ws;
  size_t off = 0;
  auto alloc = [&](size_t bytes) -> void* {
    void* p = ws + off;
    off += bytes;
    off = (off + 255) & ~(size_t)255;
    return p;
  };
  float*    ea      = (float*)   alloc((size_t)N_EDGES * 4);
  float*    csr_ea  = (float*)   alloc((size_t)N_EDGES * 4);
  int*      csr_src = (int*)     alloc((size_t)N_EDGES * 4);
  float*    easum   = (float*)   alloc((size_t)N_NODES * 4);
  int*      cnt     = (int*)     alloc((size_t)N_NODES * 4);
  int*      cnt2    = (int*)     alloc((size_t)N_NODES * 4);
  int*      rowptr  = (int*)     alloc((size_t)(N_NODES + 1) * 4);
  float*    loopat  = (float*)   alloc((size_t)N_NODES * 4);
  ushort_t* h1b     = (ushort_t*)alloc((size_t)N_NODES * GH * 2);
  float*    h2      = (float*)   alloc((size_t)N_NODES * GH * 4);
  ushort_t* h2mb    = (ushort_t*)alloc((size_t)N_NODES * HIDDEN * 2);
  int*      bsum    = (int*)     alloc(64 * 4);
  float*    pool    = (float*)   alloc((size_t)NBATCH * HIDDEN * 4);
  int*      cntg    = (int*)     alloc((size_t)NBATCH * 4);

  hipMemsetAsync(easum, 0, (size_t)N_NODES * 4, stream);
  hipMemsetAsync(cnt,   0, (size_t)N_NODES * 4, stream);
  hipMemsetAsync(cnt2,  0, (size_t)N_NODES * 4, stream);
  hipMemsetAsync(pool,  0, (size_t)NBATCH * HIDDEN * 4, stream);
  hipMemsetAsync(cntg,  0, (size_t)NBATCH * 4, stream);

  int egrid = (N_EDGES + 255) / 256;
  edge_kernel<<<egrid, 256, 0, stream>>>(ei, raw, ea, easum, cnt);
  scan_part<<<NTILES, SCAN_TPB, 0, stream>>>(cnt, easum, rowptr, loopat, bsum);
  scan_top<<<1, 64, 0, stream>>>(bsum, rowptr);
  scan_add<<<NTILES, SCAN_TPB, 0, stream>>>(rowptr, bsum);
  scatter_kernel<<<egrid, 256, 0, stream>>>(ei, ea, rowptr, cnt2, csr_src, csr_ea);

  gemm1_kernel<<<1024, 256, 0, stream>>>(x, W1, h1b);
  conv1_kernel<<<(N_NODES + 3) / 4, 256, 0, stream>>>(h1b, asrc1, adst1, We1, ae1,
      rowptr, csr_src, csr_ea, loopat, b1, g1, be1, rm1, rv1, h2);
  gemm2_kernel<<<1024, 256, 0, stream>>>(h2, W2, h2mb);
  conv2_kernel<<<(N_NODES + 3) / 4, 256, 0, stream>>>(h2mb, asrc2, adst2, We2, ae2,
      rowptr, csr_src, csr_ea, loopat, b2, g2, be2, rm2, rv2, batch, pool, cntg);
  final_kernel<<<1, 640, 0, stream>>>(pool, cntg, Wc, bc, out);
}

// Round 12
// 1005.186 us; speedup vs baseline: 1.9641x; 1.9641x over previous
//
#include <hip/hip_runtime.h>
#include <math.h>

#define N_NODES 50000
#define N_EDGES 1600000
#define NBATCH  64
#define INCH    128
#define HEADS   8
#define HD      8
#define GH      64
#define HIDDEN  64
#define NC      10
#define NEG_SLOPE 0.2f
#define BN_EPS  1e-5f

#define SCAN_TPB 1024
#define NTILES   ((N_NODES + SCAN_TPB - 1) / SCAN_TPB)   // 49

typedef unsigned short ushort_t;
typedef unsigned int uint_t;

__device__ __forceinline__ ushort_t f2bf(float f) {
  uint_t u = __float_as_uint(f);
  uint_t r = (u + 0x7fffu + ((u >> 16) & 1u)) >> 16;   // RNE
  return (ushort_t)r;
}
__device__ __forceinline__ float2 upk(uint_t u) {
  return make_float2(__uint_as_float(u << 16), __uint_as_float(u & 0xffff0000u));
}

// ---------------- edge pass ----------------
__global__ __launch_bounds__(256) void edge_kernel(
    const int* __restrict__ ei, const float* __restrict__ raw,
    float* __restrict__ ea, float* __restrict__ easum, int* __restrict__ cnt) {
  int e = blockIdx.x * blockDim.x + threadIdx.x;
  if (e >= N_EDGES) return;
  int s = ei[e], d = ei[N_EDGES + e];
  float dx = raw[s*3+0] - raw[d*3+0];
  float dy = raw[s*3+1] - raw[d*3+1];
  float dz = raw[s*3+2] - raw[d*3+2];
  float w = __expf(-2.0f * (dx*dx + dy*dy + dz*dz));
  ea[e] = w;
  atomicAdd(&easum[d], w);
  atomicAdd(&cnt[d], 1);
}

// ---------------- CSR build ----------------
__global__ __launch_bounds__(SCAN_TPB) void scan_part(
    const int* __restrict__ cnt, const float* __restrict__ easum,
    int* __restrict__ rowptr, float* __restrict__ loopat, int* __restrict__ bsum) {
  __shared__ int s[SCAN_TPB];
  int t = threadIdx.x;
  int i = blockIdx.x * SCAN_TPB + t;
  int v = (i < N_NODES) ? cnt[i] : 0;
  s[t] = v; __syncthreads();
  for (int off = 1; off < SCAN_TPB; off <<= 1) {
    int u = (t >= off) ? s[t - off] : 0;
    __syncthreads();
    s[t] += u;
    __syncthreads();
  }
  if (i < N_NODES) {
    rowptr[i] = s[t] - v;
    loopat[i] = easum[i] / fmaxf((float)v, 1.0f);
  }
  if (t == SCAN_TPB - 1) bsum[blockIdx.x] = s[t];
}

__global__ __launch_bounds__(64) void scan_top(int* __restrict__ bsum, int* __restrict__ rowptr) {
  int t = threadIdx.x;
  int v = (t < NTILES) ? bsum[t] : 0;
  int orig = v;
  for (int off = 1; off < 64; off <<= 1) {
    int u = __shfl_up(v, off);
    if (t >= off) v += u;
  }
  if (t < NTILES) bsum[t] = v - orig;
  if (t == 0) rowptr[N_NODES] = N_EDGES;
}

__global__ __launch_bounds__(SCAN_TPB) void scan_add(int* __restrict__ rowptr, const int* __restrict__ bsum) {
  int i = blockIdx.x * SCAN_TPB + threadIdx.x;
  if (i < N_NODES) rowptr[i] += bsum[blockIdx.x];
}

__global__ __launch_bounds__(256) void scatter_kernel(
    const int* __restrict__ ei, const float* __restrict__ ea,
    const int* __restrict__ rowptr, int* __restrict__ cnt2,
    int* __restrict__ csr_src, float* __restrict__ csr_ea) {
  int e = blockIdx.x * blockDim.x + threadIdx.x;
  if (e >= N_EDGES) return;
  int s = ei[e], d = ei[N_EDGES + e];
  int pos = rowptr[d] + atomicAdd(&cnt2[d], 1);
  csr_src[pos] = s;
  csr_ea[pos] = ea[e];
}

// ---------------- GEMM1: h1 = x @ W1 (bf16 rows) + fused als1/ald1 ----------------
__global__ __launch_bounds__(256) void gemm1_kernel(
    const float* __restrict__ x, const float* __restrict__ W1,
    const float* __restrict__ asrc, const float* __restrict__ adst,
    ushort_t* __restrict__ h1b, float* __restrict__ als, float* __restrict__ ald) {
  __shared__ float w[INCH * GH];   // 32 KB
  for (int i = threadIdx.x; i < INCH * GH / 4; i += blockDim.x)
    ((float4*)w)[i] = ((const float4*)W1)[i];
  __syncthreads();
  int lane = threadIdx.x & 63;
  int waveG = __builtin_amdgcn_readfirstlane((blockIdx.x * blockDim.x + threadIdx.x) >> 6);
  int nWaves = (gridDim.x * blockDim.x) >> 6;
  float a_s = asrc[lane];
  float a_d = adst[lane];
  for (int base = waveG * 4; base < N_NODES; base += nWaves * 4) {   // N % 4 == 0
    float acc[4] = {0.f, 0.f, 0.f, 0.f};
    #pragma unroll 8
    for (int k = 0; k < INCH; ++k) {
      float wv = w[k * GH + lane];
      #pragma unroll
      for (int j = 0; j < 4; ++j)
        acc[j] = fmaf(x[(size_t)(base + j) * INCH + k], wv, acc[j]);
    }
    #pragma unroll
    for (int j = 0; j < 4; ++j) {
      int n = base + j;
      float hv = acc[j];
      h1b[(size_t)n * GH + lane] = f2bf(hv);
      float ps = hv * a_s, pd = hv * a_d;
      ps += __shfl_xor(ps, 1); ps += __shfl_xor(ps, 2); ps += __shfl_xor(ps, 4);
      pd += __shfl_xor(pd, 1); pd += __shfl_xor(pd, 2); pd += __shfl_xor(pd, 4);
      if ((lane & 7) == 0) {
        als[n * HEADS + (lane >> 3)] = ps;
        ald[n * HEADS + (lane >> 3)] = pd;
      }
    }
  }
}

// ---------------- conv1: quarter layout, deep-pipelined gathers, precomputed als ----------
// lane = 16*q + i; quarter q handles edges j = slot*4 + q; lane i covers dims 4i..4i+3,
// head = i>>1. Inner loop: no dots, no shfls. Group = 4 slots (16 edges/wave per LOAD),
// double-buffered A/B -> ~32 rows in flight per wave.
__global__ __launch_bounds__(256) void conv1_kernel(
    const ushort_t* __restrict__ h1b, const float* __restrict__ als,
    const float* __restrict__ ald,
    const float* __restrict__ We, const float* __restrict__ ae,
    const int* __restrict__ rowptr,
    const int* __restrict__ csr_src, const float* __restrict__ csr_ea,
    const float* __restrict__ loopat, const float* __restrict__ bias,
    const float* __restrict__ gamma, const float* __restrict__ beta,
    const float* __restrict__ rm, const float* __restrict__ rv,
    float* __restrict__ h2) {
  __shared__ int   src_lds[4][64];
  __shared__ float ea_lds[4][64];
  int l = threadIdx.x & 63;
  int w = threadIdx.x >> 6;
  int n = blockIdx.x * 4 + w;
  if (n >= N_NODES) return;
  int i = l & 15;
  int q = l >> 4;
  int head = i >> 1;
  float4 we4 = ((const float4*)We)[i];
  float4 ae4 = ((const float4*)ae)[i];
  float ce = we4.x*ae4.x + we4.y*ae4.y + we4.z*ae4.z + we4.w*ae4.w;
  ce += __shfl_xor(ce, 1);                       // per-head edge coeff
  float aldn = ald[(size_t)n * HEADS + head];
  float als_self = als[(size_t)n * HEADS + head];
  const uint2* tab = (const uint2*)h1b;          // row = 16 x uint2
  uint2 uself = tab[(size_t)n * 16 + i];
  float2 s01 = upk(uself.x), s23 = upk(uself.y);
  int jb = rowptr[n], je = rowptr[n + 1];
  float ssum = 0.f;
  float a0 = 0.f, a1 = 0.f, a2 = 0.f, a3 = 0.f;

#define C1_LOADS(J, R, A, E)                                           \
  {                                                                    \
    int jj = (J);                                                      \
    bool vv = jj < cnt;                                                \
    int ss = vv ? src_lds[w][jj] : 0;                                  \
    R = tab[(size_t)ss * 16 + i];                                      \
    A = vv ? als[(size_t)ss * HEADS + head] : -1e30f;                  \
    E = vv ? ea_lds[w][jj] : 0.f;                                      \
  }
#define C1_LOADG(GI, R0,R1,R2,R3, A0,A1,A2,A3, E0,E1,E2,E3)            \
  {                                                                    \
    int jbase = (GI) * 16 + q;                                         \
    C1_LOADS(jbase,      R0, A0, E0)                                   \
    C1_LOADS(jbase + 4,  R1, A1, E1)                                   \
    C1_LOADS(jbase + 8,  R2, A2, E2)                                   \
    C1_LOADS(jbase + 12, R3, A3, E3)                                   \
  }
#define C1_PROC(R, A, E)                                               \
  {                                                                    \
    float2 t01 = upk(R.x), t23 = upk(R.y);                             \
    float lg = A + aldn + E * ce;                                      \
    lg = (lg >= 0.f) ? lg : NEG_SLOPE * lg;                            \
    float p = __expf(fminf(lg, 60.f));                                 \
    ssum += p;                                                         \
    a0 = fmaf(p, t01.x, a0); a1 = fmaf(p, t01.y, a1);                  \
    a2 = fmaf(p, t23.x, a2); a3 = fmaf(p, t23.y, a3);                  \
  }

  for (int cb = jb; cb < je; cb += 64) {
    int cnt = je - cb; if (cnt > 64) cnt = 64;
    src_lds[w][l] = (l < cnt) ? csr_src[cb + l] : 0;
    ea_lds[w][l]  = (l < cnt) ? csr_ea[cb + l] : 0.f;
    int ng = (cnt + 15) >> 4;
    uint2 rA0, rA1, rA2, rA3, rB0, rB1, rB2, rB3;
    float aA0, aA1, aA2, aA3, aB0, aB1, aB2, aB3;
    float eA0, eA1, eA2, eA3, eB0, eB1, eB2, eB3;
    C1_LOADG(0, rA0,rA1,rA2,rA3, aA0,aA1,aA2,aA3, eA0,eA1,eA2,eA3)
    for (int gi = 0; gi < ng; gi += 2) {
      bool hasB = (gi + 1) < ng;
      if (hasB) C1_LOADG(gi + 1, rB0,rB1,rB2,rB3, aB0,aB1,aB2,aB3, eB0,eB1,eB2,eB3)
      C1_PROC(rA0, aA0, eA0) C1_PROC(rA1, aA1, eA1)
      C1_PROC(rA2, aA2, eA2) C1_PROC(rA3, aA3, eA3)
      if (hasB) {
        if (gi + 2 < ng) C1_LOADG(gi + 2, rA0,rA1,rA2,rA3, aA0,aA1,aA2,aA3, eA0,eA1,eA2,eA3)
        C1_PROC(rB0, aB0, eB0) C1_PROC(rB1, aB1, eB1)
        C1_PROC(rB2, aB2, eB2) C1_PROC(rB3, aB3, eB3)
      }
    }
  }
#undef C1_LOADS
#undef C1_LOADG
#undef C1_PROC

  // fold across quarters (within-quarter lanes hold identical ssum; a-partials differ by q)
  ssum += __shfl_xor(ssum, 16); ssum += __shfl_xor(ssum, 32);
  a0 += __shfl_xor(a0, 16); a0 += __shfl_xor(a0, 32);
  a1 += __shfl_xor(a1, 16); a1 += __shfl_xor(a1, 32);
  a2 += __shfl_xor(a2, 16); a2 += __shfl_xor(a2, 32);
  a3 += __shfl_xor(a3, 16); a3 += __shfl_xor(a3, 32);
  // self loop — AFTER fold
  {
    float lg = als_self + aldn + loopat[n] * ce;
    lg = (lg >= 0.f) ? lg : NEG_SLOPE * lg;
    float p = __expf(fminf(lg, 60.f));
    ssum += p;
    a0 = fmaf(p, s01.x, a0); a1 = fmaf(p, s01.y, a1);
    a2 = fmaf(p, s23.x, a2); a3 = fmaf(p, s23.y, a3);
  }
  if (q == 0) {
    float inv = 1.0f / ssum;
    float4 b4 = ((const float4*)bias)[i];
    float4 g4 = ((const float4*)gamma)[i];
    float4 be4 = ((const float4*)beta)[i];
    float4 rm4 = ((const float4*)rm)[i];
    float4 rv4 = ((const float4*)rv)[i];
    float o0 = a0 * inv + b4.x, o1 = a1 * inv + b4.y;
    float o2 = a2 * inv + b4.z, o3 = a3 * inv + b4.w;
    o0 = (o0 - rm4.x) * (g4.x * rsqrtf(rv4.x + BN_EPS)) + be4.x;
    o1 = (o1 - rm4.y) * (g4.y * rsqrtf(rv4.y + BN_EPS)) + be4.y;
    o2 = (o2 - rm4.z) * (g4.z * rsqrtf(rv4.z + BN_EPS)) + be4.z;
    o3 = (o3 - rm4.w) * (g4.w * rsqrtf(rv4.w + BN_EPS)) + be4.w;
    o0 = (o0 > 0.f) ? o0 : expm1f(o0);
    o1 = (o1 > 0.f) ? o1 : expm1f(o1);
    o2 = (o2 > 0.f) ? o2 : expm1f(o2);
    o3 = (o3 > 0.f) ? o3 : expm1f(o3);
    ((float4*)(h2 + (size_t)n * GH))[i] = make_float4(o0, o1, o2, o3);
  }
}

// ---------------- GEMM2: h2m = h2 @ W2 (bf16 rows) + fused als2/ald2 ----------------
__global__ __launch_bounds__(256) void gemm2_kernel(
    const float* __restrict__ x, const float* __restrict__ W2,
    const float* __restrict__ asrc, const float* __restrict__ adst,
    ushort_t* __restrict__ h2mb, float* __restrict__ als, float* __restrict__ ald) {
  __shared__ float w[HIDDEN * HIDDEN];   // 16 KB
  for (int i = threadIdx.x; i < HIDDEN * HIDDEN / 4; i += blockDim.x)
    ((float4*)w)[i] = ((const float4*)W2)[i];
  __syncthreads();
  int lane = threadIdx.x & 63;
  int waveG = __builtin_amdgcn_readfirstlane((blockIdx.x * blockDim.x + threadIdx.x) >> 6);
  int nWaves = (gridDim.x * blockDim.x) >> 6;
  float a_s = asrc[lane];
  float a_d = adst[lane];
  for (int base = waveG * 4; base < N_NODES; base += nWaves * 4) {
    float acc[4] = {0.f, 0.f, 0.f, 0.f};
    #pragma unroll 8
    for (int k = 0; k < HIDDEN; ++k) {
      float wv = w[k * HIDDEN + lane];
      #pragma unroll
      for (int j = 0; j < 4; ++j)
        acc[j] = fmaf(x[(size_t)(base + j) * HIDDEN + k], wv, acc[j]);
    }
    #pragma unroll
    for (int j = 0; j < 4; ++j) {
      int n = base + j;
      float hv = acc[j];
      h2mb[(size_t)n * HIDDEN + lane] = f2bf(hv);
      float ps = hv * a_s, pd = hv * a_d;
      #pragma unroll
      for (int off = 1; off < 64; off <<= 1) {
        ps += __shfl_xor(ps, off);
        pd += __shfl_xor(pd, off);
      }
      if (lane == 0) { als[n] = ps; ald[n] = pd; }
    }
  }
}

// ---------------- conv2 (heads=1): quarter layout, deep-pipelined, precomputed als ------
__global__ __launch_bounds__(256) void conv2_kernel(
    const ushort_t* __restrict__ h2mb, const float* __restrict__ als,
    const float* __restrict__ ald,
    const float* __restrict__ We, const float* __restrict__ ae,
    const int* __restrict__ rowptr,
    const int* __restrict__ csr_src, const float* __restrict__ csr_ea,
    const float* __restrict__ loopat, const float* __restrict__ bias,
    const float* __restrict__ gamma, const float* __restrict__ beta,
    const float* __restrict__ rm, const float* __restrict__ rv,
    const int* __restrict__ batch,
    float* __restrict__ pool, int* __restrict__ cntg) {
  __shared__ int   src_lds[4][64];
  __shared__ float ea_lds[4][64];
  int l = threadIdx.x & 63;
  int w = threadIdx.x >> 6;
  int n = blockIdx.x * 4 + w;
  if (n >= N_NODES) return;
  int i = l & 15;
  int q = l >> 4;
  float4 we4 = ((const float4*)We)[i];
  float4 ae4 = ((const float4*)ae)[i];
  float ce = we4.x*ae4.x + we4.y*ae4.y + we4.z*ae4.z + we4.w*ae4.w;
  ce += __shfl_xor(ce, 1); ce += __shfl_xor(ce, 2);
  ce += __shfl_xor(ce, 4); ce += __shfl_xor(ce, 8);   // full 64-dim coeff
  float aldn = ald[n];
  float als_self = als[n];
  const uint2* tab = (const uint2*)h2mb;              // row = 16 x uint2
  uint2 uself = tab[(size_t)n * 16 + i];
  float2 s01 = upk(uself.x), s23 = upk(uself.y);
  int jb = rowptr[n], je = rowptr[n + 1];
  float ssum = 0.f;
  float a0 = 0.f, a1 = 0.f, a2 = 0.f, a3 = 0.f;

#define C2_LOADS(J, R, A, E)                                           \
  {                                                                    \
    int jj = (J);                                                      \
    bool vv = jj < cnt;                                                \
    int ss = vv ? src_lds[w][jj] : 0;                                  \
    R = tab[(size_t)ss * 16 + i];                                      \
    A = vv ? als[ss] : -1e30f;                                         \
    E = vv ? ea_lds[w][jj] : 0.f;                                      \
  }
#define C2_LOADG(GI, R0,R1,R2,R3, A0,A1,A2,A3, E0,E1,E2,E3)            \
  {                                                                    \
    int jbase = (GI) * 16 + q;                                         \
    C2_LOADS(jbase,      R0, A0, E0)                                   \
    C2_LOADS(jbase + 4,  R1, A1, E1)                                   \
    C2_LOADS(jbase + 8,  R2, A2, E2)                                   \
    C2_LOADS(jbase + 12, R3, A3, E3)                                   \
  }
#define C2_PROC(R, A, E)                                               \
  {                                                                    \
    float2 t01 = upk(R.x), t23 = upk(R.y);                             \
    float lg = A + aldn + E * ce;                                      \
    lg = (lg >= 0.f) ? lg : NEG_SLOPE * lg;                            \
    float p = __expf(fminf(lg, 60.f));                                 \
    ssum += p;                                                         \
    a0 = fmaf(p, t01.x, a0); a1 = fmaf(p, t01.y, a1);                  \
    a2 = fmaf(p, t23.x, a2); a3 = fmaf(p, t23.y, a3);                  \
  }

  for (int cb = jb; cb < je; cb += 64) {
    int cnt = je - cb; if (cnt > 64) cnt = 64;
    src_lds[w][l] = (l < cnt) ? csr_src[cb + l] : 0;
    ea_lds[w][l]  = (l < cnt) ? csr_ea[cb + l] : 0.f;
    int ng = (cnt + 15) >> 4;
    uint2 rA0, rA1, rA2, rA3, rB0, rB1, rB2, rB3;
    float aA0, aA1, aA2, aA3, aB0, aB1, aB2, aB3;
    float eA0, eA1, eA2, eA3, eB0, eB1, eB2, eB3;
    C2_LOADG(0, rA0,rA1,rA2,rA3, aA0,aA1,aA2,aA3, eA0,eA1,eA2,eA3)
    for (int gi = 0; gi < ng; gi += 2) {
      bool hasB = (gi + 1) < ng;
      if (hasB) C2_LOADG(gi + 1, rB0,rB1,rB2,rB3, aB0,aB1,aB2,aB3, eB0,eB1,eB2,eB3)
      C2_PROC(rA0, aA0, eA0) C2_PROC(rA1, aA1, eA1)
      C2_PROC(rA2, aA2, eA2) C2_PROC(rA3, aA3, eA3)
      if (hasB) {
        if (gi + 2 < ng) C2_LOADG(gi + 2, rA0,rA1,rA2,rA3, aA0,aA1,aA2,aA3, eA0,eA1,eA2,eA3)
        C2_PROC(rB0, aB0, eB0) C2_PROC(rB1, aB1, eB1)
        C2_PROC(rB2, aB2, eB2) C2_PROC(rB3, aB3, eB3)
      }
    }
  }
#undef C2_LOADS
#undef C2_LOADG
#undef C2_PROC

  ssum += __shfl_xor(ssum, 16); ssum += __shfl_xor(ssum, 32);
  a0 += __shfl_xor(a0, 16); a0 += __shfl_xor(a0, 32);
  a1 += __shfl_xor(a1, 16); a1 += __shfl_xor(a1, 32);
  a2 += __shfl_xor(a2, 16); a2 += __shfl_xor(a2, 32);
  a3 += __shfl_xor(a3, 16); a3 += __shfl_xor(a3, 32);
  // self loop — AFTER fold
  {
    float lg = als_self + aldn + loopat[n] * ce;
    lg = (lg >= 0.f) ? lg : NEG_SLOPE * lg;
    float p = __expf(fminf(lg, 60.f));
    ssum += p;
    a0 = fmaf(p, s01.x, a0); a1 = fmaf(p, s01.y, a1);
    a2 = fmaf(p, s23.x, a2); a3 = fmaf(p, s23.y, a3);
  }
  if (q == 0) {
    float inv = 1.0f / ssum;
    float4 b4 = ((const float4*)bias)[i];
    float4 g4 = ((const float4*)gamma)[i];
    float4 be4 = ((const float4*)beta)[i];
    float4 rm4 = ((const float4*)rm)[i];
    float4 rv4 = ((const float4*)rv)[i];
    float o0 = a0 * inv + b4.x, o1 = a1 * inv + b4.y;
    float o2 = a2 * inv + b4.z, o3 = a3 * inv + b4.w;
    o0 = (o0 - rm4.x) * (g4.x * rsqrtf(rv4.x + BN_EPS)) + be4.x;
    o1 = (o1 - rm4.y) * (g4.y * rsqrtf(rv4.y + BN_EPS)) + be4.y;
    o2 = (o2 - rm4.z) * (g4.z * rsqrtf(rv4.z + BN_EPS)) + be4.z;
    o3 = (o3 - rm4.w) * (g4.w * rsqrtf(rv4.w + BN_EPS)) + be4.w;
    o0 = (o0 > 0.f) ? o0 : expm1f(o0);
    o1 = (o1 > 0.f) ? o1 : expm1f(o1);
    o2 = (o2 > 0.f) ? o2 : expm1f(o2);
    o3 = (o3 > 0.f) ? o3 : expm1f(o3);
    int b = batch[n];
    float* pp = pool + (size_t)b * HIDDEN + 4 * i;
    atomicAdd(pp + 0, o0);
    atomicAdd(pp + 1, o1);
    atomicAdd(pp + 2, o2);
    atomicAdd(pp + 3, o3);
    if (l == 0) atomicAdd(&cntg[b], 1);
  }
}

// ---------------- classifier ----------------
__global__ __launch_bounds__(640) void final_kernel(
    const float* __restrict__ pool, const int* __restrict__ cntg,
    const float* __restrict__ Wc, const float* __restrict__ bc,
    float* __restrict__ out) {
  int t = threadIdx.x;
  if (t >= NBATCH * NC) return;
  int b = t / NC, c = t - b * NC;
  float inv = 1.0f / fmaxf((float)cntg[b], 1.0f);
  float s = bc[c];
  #pragma unroll
  for (int d = 0; d < HIDDEN; ++d)
    s = fmaf(pool[b * HIDDEN + d] * inv, Wc[d * NC + c], s);
  out[t] = s;
}

extern "C" void kernel_launch(void* const* d_in, const int* in_sizes, int n_in,
                              void* d_out, int out_size, void* d_ws, size_t ws_size,
                              hipStream_t stream) {
  const float* x     = (const float*)d_in[0];
  const float* raw   = (const float*)d_in[1];
  const int*   ei    = (const int*)  d_in[2];
  const int*   batch = (const int*)  d_in[3];
  const float* W1    = (const float*)d_in[4];
  const float* asrc1 = (const float*)d_in[5];
  const float* adst1 = (const float*)d_in[6];
  const float* We1   = (const float*)d_in[7];
  const float* ae1   = (const float*)d_in[8];
  const float* b1    = (const float*)d_in[9];
  const float* g1    = (const float*)d_in[10];
  const float* be1   = (const float*)d_in[11];
  const float* rm1   = (const float*)d_in[12];
  const float* rv1   = (const float*)d_in[13];
  const float* W2    = (const float*)d_in[14];
  const float* asrc2 = (const float*)d_in[15];
  const float* adst2 = (const float*)d_in[16];
  const float* We2   = (const float*)d_in[17];
  const float* ae2   = (const float*)d_in[18];
  const float* b2    = (const float*)d_in[19];
  const float* g2    = (const float*)d_in[20];
  const float* be2   = (const float*)d_in[21];
  const float* rm2   = (const float*)d_in[22];
  const float* rv2   = (const float*)d_in[23];
  const float* Wc    = (const float*)d_in[24];
  const float* bc    = (const float*)d_in[25];
  float* out = (float*)d_out;

  char* ws = (char*)d_ws;
  size_t off = 0;
  auto alloc = [&](size_t bytes) -> void* {
    void* p = ws + off;
    off += bytes;
    off = (off + 255) & ~(size_t)255;
    return p;
  };
  float*    ea      = (float*)   alloc((size_t)N_EDGES * 4);
  float*    csr_ea  = (float*)   alloc((size_t)N_EDGES * 4);
  int*      csr_src = (int*)     alloc((size_t)N_EDGES * 4);
  float*    easum   = (float*)   alloc((size_t)N_NODES * 4);
  int*      cnt     = (int*)     alloc((size_t)N_NODES * 4);
  int*      cnt2    = (int*)     alloc((size_t)N_NODES * 4);
  int*      rowptr  = (int*)     alloc((size_t)(N_NODES + 1) * 4);
  float*    loopat  = (float*)   alloc((size_t)N_NODES * 4);
  ushort_t* h1b     = (ushort_t*)alloc((size_t)N_NODES * GH * 2);
  float*    als1    = (float*)   alloc((size_t)N_NODES * HEADS * 4);
  float*    ald1    = (float*)   alloc((size_t)N_NODES * HEADS * 4);
  float*    h2      = (float*)   alloc((size_t)N_NODES * GH * 4);
  ushort_t* h2mb    = (ushort_t*)alloc((size_t)N_NODES * HIDDEN * 2);
  float*    als2    = (float*)   alloc((size_t)N_NODES * 4);
  float*    ald2    = (float*)   alloc((size_t)N_NODES * 4);
  int*      bsum    = (int*)     alloc(64 * 4);
  float*    pool    = (float*)   alloc((size_t)NBATCH * HIDDEN * 4);
  int*      cntg    = (int*)     alloc((size_t)NBATCH * 4);

  hipMemsetAsync(easum, 0, (size_t)N_NODES * 4, stream);
  hipMemsetAsync(cnt,   0, (size_t)N_NODES * 4, stream);
  hipMemsetAsync(cnt2,  0, (size_t)N_NODES * 4, stream);
  hipMemsetAsync(pool,  0, (size_t)NBATCH * HIDDEN * 4, stream);
  hipMemsetAsync(cntg,  0, (size_t)NBATCH * 4, stream);

  int egrid = (N_EDGES + 255) / 256;
  edge_kernel<<<egrid, 256, 0, stream>>>(ei, raw, ea, easum, cnt);
  scan_part<<<NTILES, SCAN_TPB, 0, stream>>>(cnt, easum, rowptr, loopat, bsum);
  scan_top<<<1, 64, 0, stream>>>(bsum, rowptr);
  scan_add<<<NTILES, SCAN_TPB, 0, stream>>>(rowptr, bsum);
  scatter_kernel<<<egrid, 256, 0, stream>>>(ei, ea, rowptr, cnt2, csr_src, csr_ea);

  gemm1_kernel<<<1024, 256, 0, stream>>>(x, W1, asrc1, adst1, h1b, als1, ald1);
  conv1_kernel<<<(N_NODES + 3) / 4, 256, 0, stream>>>(h1b, als1, ald1, We1, ae1,
      rowptr, csr_src, csr_ea, loopat, b1, g1, be1, rm1, rv1, h2);
  gemm2_kernel<<<1024, 256, 0, stream>>>(h2, W2, asrc2, adst2, h2mb, als2, ald2);
  conv2_kernel<<<(N_NODES + 3) / 4, 256, 0, stream>>>(h2mb, als2, ald2, We2, ae2,
      rowptr, csr_src, csr_ea, loopat, b2, g2, be2, rm2, rv2, batch, pool, cntg);
  final_kernel<<<1, 640, 0, stream>>>(pool, cntg, Wc, bc, out);
}